// Round 13
// baseline (445.231 us; speedup 1.0000x reference)
//
#include <hip/hip_runtime.h>
#include <hip/hip_bf16.h>

#define NG 100000
#define NU 100000
#define NE 3200000
#define NC 2000000

// dst-bucket binning: 128 dsts per bucket, single level, write-coalesced via
// LDS reorder (R10 config: dense gcur -- R12 proved padded counters get
// evicted by streaming writes and regress 42->71us). R13: k_sort DELETED --
// gathers consume unsorted buckets via per-dst LDS f32 accumulation
// (acc[128][F]), removing a full 12.8MB read + 12.8MB write pass.
#define BSZ 128
#define NBK 782          // ceil(NG/BSZ)
#define CAP 5120         // entries per fine bucket (mean 4096, +16 sigma)
#define B1CH 4096        // edges per bin1 block (LDS-staged single read)

typedef __attribute__((ext_vector_type(8))) short short8;
typedef __attribute__((ext_vector_type(4))) float floatx4;
typedef unsigned short ushortx8 __attribute__((ext_vector_type(8)));

// branchless SELU on the HW transcendental (6 VALU ops)
__device__ __forceinline__ float selu_f(float x) {
    const float LAM = 1.0507009873554805f;
    const float ALA = 1.7580993408473766f;  // LAM * ALPHA
    const float L2E = 1.44269504088896340736f;
    float e = __builtin_amdgcn_exp2f(fminf(x, 0.f) * L2E);
    return fmaf(LAM, fmaxf(x, 0.f), fmaf(ALA, e, -ALA));
}

__device__ __forceinline__ float bfbits2f(unsigned short u) {
    return __uint_as_float(((unsigned)u) << 16);
}

__device__ __forceinline__ unsigned short f2bfbits(float f) {
    union { __hip_bfloat16 h; unsigned short u; } cv;
    cv.h = __float2bfloat16(f);
    return cv.u;
}

__device__ __forceinline__ float ldf(const void* p, int i, int isbf) {
    return isbf ? bfbits2f(((const unsigned short*)p)[i]) : ((const float*)p)[i];
}

// ---- Binning: edges -> 782 fine buckets, write-coalesced (R10 body, dense
//      gcur). Block 0 wave 0 also computes the dtype flags (consumed by the
//      gathers/fc, which launch later -- in-order stream). -----------------
__global__ __launch_bounds__(256) void k_bin1(const void* __restrict__ edges,
        int* __restrict__ gcur, unsigned int* __restrict__ glist,
        const unsigned int* __restrict__ xw, const unsigned int* __restrict__ cw,
        int* __restrict__ flags) {
    __shared__ unsigned int tmp[B1CH];         // 16 KB  payload (s<<7)|dl
    __shared__ unsigned short tfid[B1CH];      // 8 KB   bucket id
    __shared__ unsigned int ord[B1CH];         // 16 KB  bucket-grouped payload
    __shared__ unsigned short osid[B1CH];      // 8 KB   bucket id (grouped)
    __shared__ int hist[NBK];                  // 3.1 KB
    __shared__ int lstart[NBK];                // 3.1 KB
    __shared__ int gbase[NBK];                 // 3.1 KB
    __shared__ int ofs[NBK];                   // 3.1 KB
    __shared__ int wsum[4];
    __shared__ int se64;                       // ~60.5 KB -> 2 blk/CU

    int tid = threadIdx.x;
    long long base = (long long)blockIdx.x * B1CH;
    int chunk = (int)(NE - base);
    if (chunk > B1CH) chunk = B1CH;

    // self-detect int64 vs int32 edges (wave 0); block 0 writes all flags
    if (tid < 64) {
        unsigned long long m3 =
            __ballot(((const unsigned int*)edges)[2 * tid + 1] == 0u);
        if (tid == 0) se64 = (__popcll(m3) >= 48) ? 1 : 0;
        if (blockIdx.x == 0) {
            unsigned lo = xw[tid] & 0xffffu;
            unsigned e = (lo >> 7) & 0xff;
            unsigned long long m1 = __ballot(e >= 112 && e <= 134);
            unsigned long long m2 = __ballot(cw[2 * tid + 1] == 0u);
            if (tid == 0) {
                flags[0] = (__popcll(m1) >= 32) ? 1 : 0;
                flags[1] = (__popcll(m2) >= 48) ? 1 : 0;
                flags[2] = (__popcll(m3) >= 48) ? 1 : 0;
            }
        }
    }
    for (int b = tid; b < NBK; b += 256) hist[b] = 0;
    __syncthreads();
    int e64 = se64;

    // phase A: single global read (paired) -> LDS stage + histogram
    for (int i = 0; i < B1CH / 512; ++i) {
        int idx = i * 512 + tid * 2;
        if (idx < chunk) {
            int s0, s1, d0, d1;
            if (e64) {
                const long long* el = (const long long*)edges;
                longlong2 sv = *(const longlong2*)(el + base + idx);
                longlong2 dv = *(const longlong2*)(el + NE + base + idx);
                s0 = (int)sv.x; s1 = (int)sv.y;
                d0 = (int)dv.x; d1 = (int)dv.y;
            } else {
                const int* ei = (const int*)edges;
                int2 sv = *(const int2*)(ei + base + idx);
                int2 dv = *(const int2*)(ei + NE + base + idx);
                s0 = sv.x; s1 = sv.y; d0 = dv.x; d1 = dv.y;
            }
            int f0 = d0 >> 7;                     // BSZ = 128
            tmp[idx] = ((unsigned)s0 << 7) | (unsigned)(d0 & 127);
            tfid[idx] = (unsigned short)f0;
            atomicAdd(&hist[f0], 1);
            if (idx + 1 < chunk) {
                int f1 = d1 >> 7;
                tmp[idx + 1] = ((unsigned)s1 << 7) | (unsigned)(d1 & 127);
                tfid[idx + 1] = (unsigned short)f1;
                atomicAdd(&hist[f1], 1);
            }
        }
    }
    __syncthreads();

    // phase A2: parallel exclusive scan of hist -> lstart (4 bins/thread)
    {
        int s0 = tid * 4;
        int loc[4];
        int ssum = 0;
#pragma unroll
        for (int j = 0; j < 4; ++j) {
            int b = s0 + j;
            int c = (b < NBK) ? hist[b] : 0;
            loc[j] = ssum;
            ssum += c;
        }
        int lane = tid & 63, w = tid >> 6;
        int inc = ssum;
#pragma unroll
        for (int off = 1; off < 64; off <<= 1) {
            int v = __shfl_up(inc, off, 64);
            if (lane >= off) inc += v;
        }
        if (lane == 63) wsum[w] = inc;
        __syncthreads();
        int wbase = 0;
        for (int k = 0; k < 4; ++k)
            if (k < w) wbase += wsum[k];
        int excl = wbase + inc - ssum;
#pragma unroll
        for (int j = 0; j < 4; ++j) {
            int b = s0 + j;
            if (b < NBK) lstart[b] = excl + loc[j];
        }
    }
    __syncthreads();

    // phase B: per-bucket global reservation (dense counters -- stay hot in
    // L2); ofs seeded with lstart
    for (int b = tid; b < NBK; b += 256) {
        int c = hist[b];
        gbase[b] = (c > 0) ? atomicAdd(&gcur[b], c) : 0;
        ofs[b] = lstart[b];
    }
    __syncthreads();

    // phase C: reorder within LDS into bucket-grouped order
    for (int i = 0; i < B1CH / 256; ++i) {
        int idx = i * 256 + tid;
        if (idx < chunk) {
            int f = tfid[idx];
            int pos = atomicAdd(&ofs[f], 1);
            ord[pos] = tmp[idx];
            osid[pos] = (unsigned short)f;
        }
    }
    __syncthreads();

    // phase D: coalesced write-out (consecutive lanes -> consecutive slots)
    for (int i = 0; i < B1CH / 256; ++i) {
        int idx = i * 256 + tid;
        if (idx < chunk) {
            int f = osid[idx];
            int p = gbase[f] + (idx - lstart[f]);
            if (p < CAP) glist[(long long)f * CAP + p] = ord[idx];
        }
    }
}

// ---- Gather+Node 1, bucket-fused (R13): one block per bucket, per-dst LDS
//      f32 accumulators. No CSR, no sorted list. Entries (s<<7)|dl decoded
//      on the fly; ds_add_f32 into acc[dl][c]; epilogue computes
//      h[d] = selu(agg @ W1r + x_g[d] @ W1o + b1) for the 128 dsts. --------
__global__ __launch_bounds__(256) void k_gather1(const int* __restrict__ gcur,
        const unsigned int* __restrict__ glist, const void* __restrict__ xg,
        const void* __restrict__ W1r, const void* __restrict__ W1o,
        const void* __restrict__ b1, unsigned short* __restrict__ hbf,
        const int* __restrict__ flags) {
    __shared__ float acc[BSZ][4];     // 2 KB -> high occupancy
    int b = blockIdx.x;
    int tid = threadIdx.x;
    int isbf = flags[0];
    int cnt = gcur[b];
    if (cnt > CAP) cnt = CAP;
    const unsigned int* lp = glist + (long long)b * CAP;

    float* pa = &acc[0][0];
    for (int i = tid; i < BSZ * 4; i += 256) pa[i] = 0.f;
    __syncthreads();

    if (isbf) {
        const unsigned short* xp = (const unsigned short*)xg;
        for (int k = tid; k < cnt; k += 256) {
            unsigned u = lp[k];
            int s = (int)(u >> 7), dl = (int)(u & 127);
            ushort4 r = *(const ushort4*)(xp + s * 4);
            atomicAdd(&acc[dl][0], bfbits2f(r.x));
            atomicAdd(&acc[dl][1], bfbits2f(r.y));
            atomicAdd(&acc[dl][2], bfbits2f(r.z));
            atomicAdd(&acc[dl][3], bfbits2f(r.w));
        }
    } else {
        const float* xp = (const float*)xg;
        for (int k = tid; k < cnt; k += 256) {
            unsigned u = lp[k];
            int s = (int)(u >> 7), dl = (int)(u & 127);
            float4 r = *(const float4*)(xp + s * 4);
            atomicAdd(&acc[dl][0], r.x);
            atomicAdd(&acc[dl][1], r.y);
            atomicAdd(&acc[dl][2], r.z);
            atomicAdd(&acc[dl][3], r.w);
        }
    }
    __syncthreads();

    // epilogue: tid -> dst dl=tid>>1, outputs q0..q0+3 (q0 = (tid&1)*4)
    int dl = tid >> 1;
    int d = b * BSZ + dl;
    if (d >= NG) return;
    int q0 = (tid & 1) * 4;
    float a0 = acc[dl][0], a1 = acc[dl][1], a2 = acc[dl][2], a3 = acc[dl][3];
    float o[4];
    if (isbf) {
        const unsigned short* xp = (const unsigned short*)xg;
        const unsigned short* wr = (const unsigned short*)W1r;
        const unsigned short* wo = (const unsigned short*)W1o;
        const unsigned short* bp = (const unsigned short*)b1;
        float x0 = bfbits2f(xp[d * 4 + 0]), x1 = bfbits2f(xp[d * 4 + 1]);
        float x2 = bfbits2f(xp[d * 4 + 2]), x3 = bfbits2f(xp[d * 4 + 3]);
#pragma unroll
        for (int j = 0; j < 4; ++j) {
            int q = q0 + j;
            float v = bfbits2f(bp[q]);
            v += a0 * bfbits2f(wr[0 * 8 + q]) + a1 * bfbits2f(wr[1 * 8 + q])
               + a2 * bfbits2f(wr[2 * 8 + q]) + a3 * bfbits2f(wr[3 * 8 + q]);
            v += x0 * bfbits2f(wo[0 * 8 + q]) + x1 * bfbits2f(wo[1 * 8 + q])
               + x2 * bfbits2f(wo[2 * 8 + q]) + x3 * bfbits2f(wo[3 * 8 + q]);
            o[j] = selu_f(v);
        }
    } else {
        const float* xp = (const float*)xg;
        const float* wr = (const float*)W1r;
        const float* wo = (const float*)W1o;
        const float* bp = (const float*)b1;
        float x0 = xp[d * 4 + 0], x1 = xp[d * 4 + 1];
        float x2 = xp[d * 4 + 2], x3 = xp[d * 4 + 3];
#pragma unroll
        for (int j = 0; j < 4; ++j) {
            int q = q0 + j;
            float v = bp[q];
            v += a0 * wr[0 * 8 + q] + a1 * wr[1 * 8 + q]
               + a2 * wr[2 * 8 + q] + a3 * wr[3 * 8 + q];
            v += x0 * wo[0 * 8 + q] + x1 * wo[1 * 8 + q]
               + x2 * wo[2 * 8 + q] + x3 * wo[3 * 8 + q];
            o[j] = selu_f(v);
        }
    }
    ushort4 w;
    w.x = f2bfbits(o[0]); w.y = f2bfbits(o[1]);
    w.z = f2bfbits(o[2]); w.w = f2bfbits(o[3]);
    *(ushort4*)(hbf + d * 8 + q0) = w;
}

#define UCBLK ((NU + 255) / 256)        // 391 unconn blocks

// ---- Gather+Node 2, bucket-fused + fc_unconnected as extra grid blocks. ---
__global__ __launch_bounds__(256) void k_gather2(const int* __restrict__ gcur,
        const unsigned int* __restrict__ glist, const ushortx8* __restrict__ hbf,
        const void* __restrict__ W2r, const void* __restrict__ W2o,
        const void* __restrict__ b2, unsigned short* __restrict__ xs,
        const void* __restrict__ xu, const void* __restrict__ Wun,
        const void* __restrict__ bun, const int* __restrict__ flags) {
    int isbf = flags[0];
    int tid = threadIdx.x;
    if (blockIdx.x >= NBK) {
        // ---- unconn path: x_u @ W_un + b_un -> xs[NG:], no selu ----
        int u = (blockIdx.x - NBK) * 256 + tid;
        if (u >= NU) return;
        float x[4];
#pragma unroll
        for (int k = 0; k < 4; ++k) x[k] = ldf(xu, u * 4 + k, isbf);
        ushortx8 lo, hi;
#pragma unroll
        for (int j = 0; j < 16; ++j) {
            float v = ldf(bun, j, isbf);
#pragma unroll
            for (int k = 0; k < 4; ++k)
                v += x[k] * ldf(Wun, k * 16 + j, isbf);
            unsigned short bb = f2bfbits(v);
            if (j < 8) lo[j] = bb; else hi[j - 8] = bb;
        }
        ushortx8* xp = (ushortx8*)(xs + (NG + u) * 16);
        xp[0] = lo;
        xp[1] = hi;
        return;
    }
    __shared__ float acc[BSZ][8];     // 4 KB
    int b = blockIdx.x;
    int cnt = gcur[b];
    if (cnt > CAP) cnt = CAP;
    const unsigned int* lp = glist + (long long)b * CAP;

    float* pa = &acc[0][0];
    for (int i = tid; i < BSZ * 8; i += 256) pa[i] = 0.f;
    __syncthreads();

    for (int k = tid; k < cnt; k += 256) {
        unsigned u = lp[k];
        int s = (int)(u >> 7), dl = (int)(u & 127);
        ushortx8 r = hbf[s];
#pragma unroll
        for (int c = 0; c < 8; ++c)
            atomicAdd(&acc[dl][c], bfbits2f((unsigned short)r[c]));
    }
    __syncthreads();

    // epilogue: dst dl=tid>>1, outputs q0..q0+7 (q0 = (tid&1)*8)
    int dl = tid >> 1;
    int d = b * BSZ + dl;
    if (d >= NG) return;
    int q0 = (tid & 1) * 8;
    float av[8];
#pragma unroll
    for (int c = 0; c < 8; ++c) av[c] = acc[dl][c];
    ushortx8 hr = hbf[d];
    float hv[8];
#pragma unroll
    for (int c = 0; c < 8; ++c) hv[c] = bfbits2f((unsigned short)hr[c]);
    ushortx8 w;
    if (isbf) {
        const unsigned short* wr = (const unsigned short*)W2r;
        const unsigned short* wo = (const unsigned short*)W2o;
        const unsigned short* bp = (const unsigned short*)b2;
#pragma unroll
        for (int j = 0; j < 8; ++j) {
            int q = q0 + j;
            float v = bfbits2f(bp[q]);
#pragma unroll
            for (int c = 0; c < 8; ++c)
                v += av[c] * bfbits2f(wr[c * 16 + q])
                   + hv[c] * bfbits2f(wo[c * 16 + q]);
            w[j] = (short)f2bfbits(selu_f(v));
        }
    } else {
        const float* wr = (const float*)W2r;
        const float* wo = (const float*)W2o;
        const float* bp = (const float*)b2;
#pragma unroll
        for (int j = 0; j < 8; ++j) {
            int q = q0 + j;
            float v = bp[q];
#pragma unroll
            for (int c = 0; c < 8; ++c)
                v += av[c] * wr[c * 16 + q] + hv[c] * wo[c * 16 + q];
            w[j] = (short)f2bfbits(selu_f(v));
        }
    }
    *(ushortx8*)(xs + d * 16 + q0) = w;
}

// per-lane candidate ROW index: lane half-group hp=half>>1 selects endpoint.
// c64: low 32 bits of int64 little-endian at int-index 2*(2c+hp).
__device__ __forceinline__ int ld_candrow(const void* cand, int c, int hp, int c64) {
    const int* ci = (const int*)cand;
    return c64 ? ci[(2 * c + hp) * 2] : ci[2 * c + hp];
}

// ---- FC head: persistent waves, 4-deep software-pipelined gather.
//      Split into two half-range dispatches for rocprof visibility. --------
__global__ __launch_bounds__(256, 5) void k_fc(const unsigned short* __restrict__ xs,
        const void* __restrict__ cand,
        const void* __restrict__ Wfc1, const void* __restrict__ bfc1,
        const void* __restrict__ Wfc2, const void* __restrict__ bfc2,
        void* __restrict__ out, const int* __restrict__ flags,
        int t0, int t1) {
    const float LAM = 1.0507009873554805f;
    const float ALA = 1.7580993408473766f;  // LAM * ALPHA
    const float L2E = 1.44269504088896340736f;
    const float AR2 = 1.6732632423543772f * 1.44269504088896340736f;  // ALPHA*L2E
    const float SCL = 1.0507009873554805f / 1.44269504088896340736f;  // LAM/L2E
    int lane = threadIdx.x & 63;
    int wid = (blockIdx.x * blockDim.x + threadIdx.x) >> 6;
    int m = lane & 15;
    int half = lane >> 4;
    int isbf = flags[0], c64 = flags[1];

    short8 wfrag[4];
    floatx4 cbias[4];
    float w2s[4][4];
    float c_corr;
    if (isbf) {
        const unsigned short* W1p = (const unsigned short*)Wfc1;
#pragma unroll
        for (int t = 0; t < 4; ++t)
#pragma unroll
            for (int j = 0; j < 8; ++j)
                wfrag[t][j] = (short)f2bfbits(
                    bfbits2f(W1p[(half * 8 + j) * 64 + t * 16 + m]) * L2E);
        const unsigned short* b1p = (const unsigned short*)bfc1;
        const unsigned short* w2p = (const unsigned short*)Wfc2;
        float asum = 0.f;
#pragma unroll
        for (int t = 0; t < 4; ++t)
#pragma unroll
            for (int r = 0; r < 4; ++r) {
                int h = t * 16 + half * 4 + r;
                cbias[t][r] = bfbits2f(b1p[h]) * L2E;
                float w2 = bfbits2f(w2p[h]);
                w2s[t][r] = w2 * SCL;
                asum += w2 * ALA;
            }
        asum += __shfl_xor(asum, 16, 64);
        asum += __shfl_xor(asum, 32, 64);
        c_corr = bfbits2f(((const unsigned short*)bfc2)[0]) - asum;
    } else {
        const float* W1p = (const float*)Wfc1;
#pragma unroll
        for (int t = 0; t < 4; ++t)
#pragma unroll
            for (int j = 0; j < 8; ++j)
                wfrag[t][j] = (short)f2bfbits(
                    W1p[(half * 8 + j) * 64 + t * 16 + m] * L2E);
        const float* b1p = (const float*)bfc1;
        const float* w2p = (const float*)Wfc2;
        float asum = 0.f;
#pragma unroll
        for (int t = 0; t < 4; ++t)
#pragma unroll
            for (int r = 0; r < 4; ++r) {
                int h = t * 16 + half * 4 + r;
                cbias[t][r] = b1p[h] * L2E;
                float w2 = w2p[h];
                w2s[t][r] = w2 * SCL;
                asum += w2 * ALA;
            }
        asum += __shfl_xor(asum, 16, 64);
        asum += __shfl_xor(asum, 32, 64);
        c_corr = ((const float*)bfc2)[0] - asum;
    }

    int nW = (gridDim.x * blockDim.x) >> 6;
    if (t0 + wid >= t1) return;
    int tw = t0 + wid;   // this wave's first tile (valid fallback index)

    int half1 = half & 1;
    int hp = half >> 1;
    // 4-deep gather pipeline: af for tiles tw..tw+3nW in flight; row-index
    // queue one tile further ahead.
    int q1 = tw + nW, q2 = tw + 2 * nW, q3 = tw + 3 * nW, q4 = tw + 4 * nW;
    int r0i = ld_candrow(cand, tw * 16 + m, hp, c64);
    int r1i = ld_candrow(cand, ((q1 < t1) ? q1 : tw) * 16 + m, hp, c64);
    int r2i = ld_candrow(cand, ((q2 < t1) ? q2 : tw) * 16 + m, hp, c64);
    int r3i = ld_candrow(cand, ((q3 < t1) ? q3 : tw) * 16 + m, hp, c64);
    int r4i = ld_candrow(cand, ((q4 < t1) ? q4 : tw) * 16 + m, hp, c64);
    {
        short8 af0 = *(const short8*)(xs + r0i * 16 + half1 * 8);
        short8 af1 = *(const short8*)(xs + r1i * 16 + half1 * 8);
        short8 af2 = *(const short8*)(xs + r2i * 16 + half1 * 8);
        short8 af3 = *(const short8*)(xs + r3i * 16 + half1 * 8);

#pragma unroll 2
        for (int t = tw; t < t1; t += nW) {
            int tn5 = t + 5 * nW;
            int r5i = ld_candrow(cand, ((tn5 < t1) ? tn5 : t) * 16 + m, hp, c64);
            short8 af4 = *(const short8*)(xs + r4i * 16 + half1 * 8);

            float ps[4];
#pragma unroll
            for (int tt = 0; tt < 4; ++tt) {
                floatx4 ac = __builtin_amdgcn_mfma_f32_16x16x32_bf16(
                    wfrag[tt], af0, cbias[tt], 0, 0, 0);
                float s = 0.f;
#pragma unroll
                for (int r = 0; r < 4; ++r) {
                    float v = ac[r];
                    float mx = fmaxf(v, 0.f);
                    float e = __builtin_amdgcn_exp2f(fminf(v, 0.f));
                    s = fmaf(w2s[tt][r], fmaf(AR2, e, mx), s);
                }
                ps[tt] = s;
            }
            float part = (ps[0] + ps[1]) + (ps[2] + ps[3]);
            part += __shfl_xor(part, 16, 64);
            part += __shfl_xor(part, 32, 64);
            if (half == 0) {
                float o = part + c_corr;
                if (isbf) ((unsigned short*)out)[t * 16 + m] = f2bfbits(o);
                else ((float*)out)[t * 16 + m] = o;
            }
            af0 = af1;
            af1 = af2;
            af2 = af3;
            af3 = af4;
            r4i = r5i;
        }
    }
}

extern "C" void kernel_launch(void* const* d_in, const int* in_sizes, int n_in,
                              void* d_out, int out_size, void* d_ws, size_t ws_size,
                              hipStream_t stream) {
    const void* x_u = d_in[0];
    const void* x_g = d_in[1];
    const void* cand = d_in[2];
    const void* edges = d_in[3];
    const void* W1r = d_in[4];
    const void* W1o = d_in[5];
    const void* b1 = d_in[6];
    const void* W2r = d_in[7];
    const void* W2o = d_in[8];
    const void* b2 = d_in[9];
    const void* Wun = d_in[10];
    const void* bun = d_in[11];
    const void* Wfc1 = d_in[12];
    const void* bfc1 = d_in[13];
    const void* Wfc2 = d_in[14];
    const void* bfc2 = d_in[15];

    char* ws = (char*)d_ws;
    int* flags = (int*)ws;                                  // 64 B
    int* gcur = (int*)(ws + 64);                            // 782*4 -> 3200 B
    unsigned int* glist = (unsigned int*)(ws + 4160);       // 16.01 MB
    size_t glist_bytes = (size_t)NBK * CAP * 4;             // 16010240
    char* p = ws + 4160 + glist_bytes;
    unsigned short* hbf = (unsigned short*)p;               // 1.6 MB
    unsigned short* xs = (unsigned short*)(p + 1600000);    // 6.4 MB

    hipMemsetAsync(gcur, 0, 3200, stream);

    k_bin1<<<(NE + B1CH - 1) / B1CH, 256, 0, stream>>>(edges, gcur, glist,
                                                       (const unsigned int*)x_u,
                                                       (const unsigned int*)cand,
                                                       flags);
    k_gather1<<<NBK, 256, 0, stream>>>(gcur, glist, x_g, W1r, W1o, b1, hbf, flags);
    k_gather2<<<NBK + UCBLK, 256, 0, stream>>>(gcur, glist,
                                               (const ushortx8*)hbf,
                                               W2r, W2o, b2, xs,
                                               x_u, Wun, bun, flags);
    const int nTiles = NC / 16;          // 125000
    const int tMid = nTiles / 2;         // 62500
    k_fc<<<1280, 256, 0, stream>>>(xs, cand, Wfc1, bfc1, Wfc2, bfc2, d_out, flags,
                                   0, tMid);
    k_fc<<<1280, 256, 0, stream>>>(xs, cand, Wfc1, bfc1, Wfc2, bfc2, d_out, flags,
                                   tMid, nTiles);
}

// Round 14
// 246.112 us; speedup vs baseline: 1.8091x; 1.8091x over previous
//
#include <hip/hip_runtime.h>
#include <hip/hip_bf16.h>

#define NG 100000
#define NU 100000
#define NE 3200000
#define NC 2000000

// dst-bucket binning: 128 dsts per bucket, single level (R6), write-coalesced
// via LDS reorder (R10: WRITE_SIZE 74->27 MB, bin1 55->42us). R14: reverted
// to the R10 configuration (best measured, 253.1us) after R11 (occupancy),
// R12 (padded counters), R13 (LDS-atomic gathers) all regressed; k_fc
// re-merged into one dispatch (split was rocprof-visibility only).
#define BSZ 128
#define NBK 782          // ceil(NG/BSZ)
#define CAP 5120         // entries per fine bucket (mean 4096, +16 sigma)
#define B1CH 4096        // edges per bin1 block (LDS-staged single read)

typedef __attribute__((ext_vector_type(8))) short short8;
typedef __attribute__((ext_vector_type(4))) float floatx4;
typedef unsigned short ushortx8 __attribute__((ext_vector_type(8)));

// branchless SELU on the HW transcendental (6 VALU ops)
__device__ __forceinline__ float selu_f(float x) {
    const float LAM = 1.0507009873554805f;
    const float ALA = 1.7580993408473766f;  // LAM * ALPHA
    const float L2E = 1.44269504088896340736f;
    float e = __builtin_amdgcn_exp2f(fminf(x, 0.f) * L2E);
    return fmaf(LAM, fmaxf(x, 0.f), fmaf(ALA, e, -ALA));
}

__device__ __forceinline__ float bfbits2f(unsigned short u) {
    return __uint_as_float(((unsigned)u) << 16);
}

__device__ __forceinline__ unsigned short f2bfbits(float f) {
    union { __hip_bfloat16 h; unsigned short u; } cv;
    cv.h = __float2bfloat16(f);
    return cv.u;
}

__device__ __forceinline__ float ldf(const void* p, int i, int isbf) {
    return isbf ? bfbits2f(((const unsigned short*)p)[i]) : ((const float*)p)[i];
}

// ---- Binning: edges -> 782 fine buckets, write-coalesced (R10 body).
//      A: stage+histogram. A2: parallel exclusive scan of hist -> lstart.
//      B: per-bucket global reservation (dense counters stay hot in L2 --
//      R12 proved padded counters get evicted and regress). C: reorder into
//      bucket-grouped ord. D: coalesced run write-out. ---------------------
__global__ __launch_bounds__(256) void k_bin1(const void* __restrict__ edges,
        int* __restrict__ gcur, unsigned int* __restrict__ glist) {
    __shared__ unsigned int tmp[B1CH];         // 16 KB  payload (s<<7)|dl
    __shared__ unsigned short tfid[B1CH];      // 8 KB   bucket id
    __shared__ unsigned int ord[B1CH];         // 16 KB  bucket-grouped payload
    __shared__ unsigned short osid[B1CH];      // 8 KB   bucket id (grouped)
    __shared__ int hist[NBK];                  // 3.1 KB
    __shared__ int lstart[NBK];                // 3.1 KB
    __shared__ int gbase[NBK];                 // 3.1 KB
    __shared__ int ofs[NBK];                   // 3.1 KB
    __shared__ int wsum[4];
    __shared__ int se64;                       // ~60.5 KB -> 2 blk/CU

    int tid = threadIdx.x;
    long long base = (long long)blockIdx.x * B1CH;
    int chunk = (int)(NE - base);
    if (chunk > B1CH) chunk = B1CH;

    // self-detect int64 vs int32 edges (wave 0)
    if (tid < 64) {
        unsigned long long m3 =
            __ballot(((const unsigned int*)edges)[2 * tid + 1] == 0u);
        if (tid == 0) se64 = (__popcll(m3) >= 48) ? 1 : 0;
    }
    for (int b = tid; b < NBK; b += 256) hist[b] = 0;
    __syncthreads();
    int e64 = se64;

    // phase A: single global read (paired) -> LDS stage + histogram
    for (int i = 0; i < B1CH / 512; ++i) {
        int idx = i * 512 + tid * 2;
        if (idx < chunk) {
            int s0, s1, d0, d1;
            if (e64) {
                const long long* el = (const long long*)edges;
                longlong2 sv = *(const longlong2*)(el + base + idx);
                longlong2 dv = *(const longlong2*)(el + NE + base + idx);
                s0 = (int)sv.x; s1 = (int)sv.y;
                d0 = (int)dv.x; d1 = (int)dv.y;
            } else {
                const int* ei = (const int*)edges;
                int2 sv = *(const int2*)(ei + base + idx);
                int2 dv = *(const int2*)(ei + NE + base + idx);
                s0 = sv.x; s1 = sv.y; d0 = dv.x; d1 = dv.y;
            }
            int f0 = d0 >> 7;                     // BSZ = 128
            tmp[idx] = ((unsigned)s0 << 7) | (unsigned)(d0 & 127);
            tfid[idx] = (unsigned short)f0;
            atomicAdd(&hist[f0], 1);
            if (idx + 1 < chunk) {
                int f1 = d1 >> 7;
                tmp[idx + 1] = ((unsigned)s1 << 7) | (unsigned)(d1 & 127);
                tfid[idx + 1] = (unsigned short)f1;
                atomicAdd(&hist[f1], 1);
            }
        }
    }
    __syncthreads();

    // phase A2: parallel exclusive scan of hist -> lstart (4 bins/thread)
    {
        int s0 = tid * 4;
        int loc[4];
        int ssum = 0;
#pragma unroll
        for (int j = 0; j < 4; ++j) {
            int b = s0 + j;
            int c = (b < NBK) ? hist[b] : 0;
            loc[j] = ssum;
            ssum += c;
        }
        int lane = tid & 63, w = tid >> 6;
        int inc = ssum;
#pragma unroll
        for (int off = 1; off < 64; off <<= 1) {
            int v = __shfl_up(inc, off, 64);
            if (lane >= off) inc += v;
        }
        if (lane == 63) wsum[w] = inc;
        __syncthreads();
        int wbase = 0;
        for (int k = 0; k < 4; ++k)
            if (k < w) wbase += wsum[k];
        int excl = wbase + inc - ssum;
#pragma unroll
        for (int j = 0; j < 4; ++j) {
            int b = s0 + j;
            if (b < NBK) lstart[b] = excl + loc[j];
        }
    }
    __syncthreads();

    // phase B: per-bucket global reservation; ofs seeded with lstart
    for (int b = tid; b < NBK; b += 256) {
        int c = hist[b];
        gbase[b] = (c > 0) ? atomicAdd(&gcur[b], c) : 0;
        ofs[b] = lstart[b];
    }
    __syncthreads();

    // phase C: reorder within LDS into bucket-grouped order
    for (int i = 0; i < B1CH / 256; ++i) {
        int idx = i * 256 + tid;
        if (idx < chunk) {
            int f = tfid[idx];
            int pos = atomicAdd(&ofs[f], 1);
            ord[pos] = tmp[idx];
            osid[pos] = (unsigned short)f;
        }
    }
    __syncthreads();

    // phase D: coalesced write-out (consecutive lanes -> consecutive slots)
    for (int i = 0; i < B1CH / 256; ++i) {
        int idx = i * 256 + tid;
        if (idx < chunk) {
            int f = osid[idx];
            int p = gbase[f] + (idx - lstart[f]);
            if (p < CAP) glist[(long long)f * CAP + p] = ord[idx];
        }
    }
}

// ---- Counting-sort each bucket by dl; direct final write (bucket-local
//      window, L2-absorbed). Block 0 wave 0 computes dtype flags. ----------
__global__ __launch_bounds__(256) void k_sort(const int* __restrict__ gcur,
        unsigned int* __restrict__ glist,
        int* __restrict__ dstoff, int* __restrict__ ddeg,
        const unsigned int* __restrict__ xw, const unsigned int* __restrict__ cw,
        const unsigned int* __restrict__ ew, int* __restrict__ flags) {
    __shared__ unsigned int tmp[CAP];      // 20 KB
    __shared__ int hist[BSZ];
    __shared__ int cur[BSZ];
    __shared__ int wtot;                   // ~21.3 KB -> 7 blocks/CU
    int b = blockIdx.x;
    int tid = threadIdx.x;

    if (b == 0 && tid < 64) {
        unsigned lo = xw[tid] & 0xffffu;
        unsigned e = (lo >> 7) & 0xff;
        unsigned long long m1 = __ballot(e >= 112 && e <= 134);
        unsigned long long m2 = __ballot(cw[2 * tid + 1] == 0u);
        unsigned long long m3 = __ballot(ew[2 * tid + 1] == 0u);
        if (tid == 0) {
            flags[0] = (__popcll(m1) >= 32) ? 1 : 0;
            flags[1] = (__popcll(m2) >= 48) ? 1 : 0;
            flags[2] = (__popcll(m3) >= 48) ? 1 : 0;
        }
    }

    int cnt = gcur[b];
    if (cnt > CAP) cnt = CAP;
    unsigned int* lp = glist + (long long)b * CAP;

    if (tid < BSZ) hist[tid] = 0;
    __syncthreads();
    // single global read -> LDS + histogram
    for (int k = tid; k < cnt; k += 256) {
        unsigned u = lp[k];
        tmp[k] = u;
        atomicAdd(&hist[u & 127], 1);
    }
    __syncthreads();
    // inclusive scan of hist[0..127] across 2 waves via shfl_up
    int h = (tid < BSZ) ? hist[tid] : 0;
    int s = h;
#pragma unroll
    for (int off = 1; off < 64; off <<= 1) {
        int v = __shfl_up(s, off, 64);
        if ((tid & 63) >= off) s += v;
    }
    if (tid == 63) wtot = s;
    __syncthreads();
    if (tid >= 64 && tid < BSZ) s += wtot;
    if (tid < BSZ) {
        int excl = s - h;
        cur[tid] = excl;
        int d = b * BSZ + tid;
        if (d < NG) {
            dstoff[d] = b * CAP + excl;
            ddeg[d] = h;
        }
    }
    __syncthreads();
    // direct final write (reads of lp fully drained pre-barrier)
    for (int k = tid; k < cnt; k += 256) {
        unsigned u = tmp[k];
        int pos = atomicAdd(&cur[u & 127], 1);
        lp[pos] = u >> 7;
    }
}

// ---- Gather+Node 1 fused: 16 threads/dst, paired independent gathers.
//      isbf hoisted out of the edge loop (wave-uniform). -------------------
__global__ __launch_bounds__(256) void k_gather1(const int* __restrict__ dstoff,
        const int* __restrict__ ddeg, const unsigned int* __restrict__ glist,
        const void* __restrict__ xg,
        const void* __restrict__ W1r, const void* __restrict__ W1o,
        const void* __restrict__ b1, unsigned short* __restrict__ hbf,
        const int* __restrict__ flags) {
    int gid = blockIdx.x * 256 + threadIdx.x;
    int d = gid >> 4;
    if (d >= NG) return;
    int q = gid & 15;
    int isbf = flags[0];
    int start = dstoff[d];
    int deg = ddeg[d];
    float a0 = 0.f, a1 = 0.f, a2 = 0.f, a3 = 0.f;
    if (isbf) {
        const unsigned short* xp = (const unsigned short*)xg;
        int k = q;
        for (; k + 16 < deg; k += 32) {
            int s0 = glist[start + k];
            int s1 = glist[start + k + 16];
            ushort4 r0 = *(const ushort4*)(xp + s0 * 4);
            ushort4 r1 = *(const ushort4*)(xp + s1 * 4);
            a0 += bfbits2f(r0.x) + bfbits2f(r1.x);
            a1 += bfbits2f(r0.y) + bfbits2f(r1.y);
            a2 += bfbits2f(r0.z) + bfbits2f(r1.z);
            a3 += bfbits2f(r0.w) + bfbits2f(r1.w);
        }
        for (; k < deg; k += 16) {
            int s = glist[start + k];
            ushort4 r = *(const ushort4*)(xp + s * 4);
            a0 += bfbits2f(r.x); a1 += bfbits2f(r.y);
            a2 += bfbits2f(r.z); a3 += bfbits2f(r.w);
        }
    } else {
        const float* xp = (const float*)xg;
        int k = q;
        for (; k + 16 < deg; k += 32) {
            int s0 = glist[start + k];
            int s1 = glist[start + k + 16];
            float4 r0 = *(const float4*)(xp + s0 * 4);
            float4 r1 = *(const float4*)(xp + s1 * 4);
            a0 += r0.x + r1.x;
            a1 += r0.y + r1.y;
            a2 += r0.z + r1.z;
            a3 += r0.w + r1.w;
        }
        for (; k < deg; k += 16) {
            int s = glist[start + k];
            float4 r = *(const float4*)(xp + s * 4);
            a0 += r.x; a1 += r.y; a2 += r.z; a3 += r.w;
        }
    }
#pragma unroll
    for (int off = 1; off < 16; off <<= 1) {
        a0 += __shfl_xor(a0, off);
        a1 += __shfl_xor(a1, off);
        a2 += __shfl_xor(a2, off);
        a3 += __shfl_xor(a3, off);
    }
    if (q < 8) {
        float a[4] = {a0, a1, a2, a3};
        float v = ldf(b1, q, isbf);
#pragma unroll
        for (int c = 0; c < 4; ++c)
            v += a[c] * ldf(W1r, c * 8 + q, isbf)
               + ldf(xg, d * 4 + c, isbf) * ldf(W1o, c * 8 + q, isbf);
        hbf[d * 8 + q] = f2bfbits(selu_f(v));
    }
}

#define G2BLK ((16 * NG + 255) / 256)   // 6250 gather2 blocks
#define UCBLK ((NU + 255) / 256)        // 391 unconn blocks

// ---- Gather+Node 2 fused + fc_unconnected (unconn as extra grid blocks). --
__global__ __launch_bounds__(256) void k_gather2(const int* __restrict__ dstoff,
        const int* __restrict__ ddeg, const unsigned int* __restrict__ glist,
        const ushortx8* __restrict__ hbf,
        const void* __restrict__ W2r, const void* __restrict__ W2o,
        const void* __restrict__ b2, unsigned short* __restrict__ xs,
        const void* __restrict__ xu, const void* __restrict__ Wun,
        const void* __restrict__ bun, const int* __restrict__ flags) {
    int isbf = flags[0];
    if (blockIdx.x >= G2BLK) {
        // ---- unconn path: x_u @ W_un + b_un -> xs[NG:], no selu ----
        int u = (blockIdx.x - G2BLK) * 256 + threadIdx.x;
        if (u >= NU) return;
        float x[4];
#pragma unroll
        for (int k = 0; k < 4; ++k) x[k] = ldf(xu, u * 4 + k, isbf);
        ushortx8 lo, hi;
#pragma unroll
        for (int j = 0; j < 16; ++j) {
            float v = ldf(bun, j, isbf);
#pragma unroll
            for (int k = 0; k < 4; ++k)
                v += x[k] * ldf(Wun, k * 16 + j, isbf);
            unsigned short bb = f2bfbits(v);
            if (j < 8) lo[j] = bb; else hi[j - 8] = bb;
        }
        ushortx8* xp = (ushortx8*)(xs + (NG + u) * 16);
        xp[0] = lo;
        xp[1] = hi;
        return;
    }
    int gid = blockIdx.x * 256 + threadIdx.x;
    int d = gid >> 4;
    if (d >= NG) return;
    int q = gid & 15;
    int start = dstoff[d];
    int deg = ddeg[d];
    float a[8] = {0.f, 0.f, 0.f, 0.f, 0.f, 0.f, 0.f, 0.f};
    int k = q;
    for (; k + 16 < deg; k += 32) {
        int s0 = glist[start + k];
        int s1 = glist[start + k + 16];
        ushortx8 r0 = hbf[s0];
        ushortx8 r1 = hbf[s1];
#pragma unroll
        for (int c = 0; c < 8; ++c)
            a[c] += bfbits2f((unsigned short)r0[c]) + bfbits2f((unsigned short)r1[c]);
    }
    for (; k < deg; k += 16) {
        int s = glist[start + k];
        ushortx8 r = hbf[s];
#pragma unroll
        for (int c = 0; c < 8; ++c) a[c] += bfbits2f((unsigned short)r[c]);
    }
#pragma unroll
    for (int off = 1; off < 16; off <<= 1) {
#pragma unroll
        for (int c = 0; c < 8; ++c) a[c] += __shfl_xor(a[c], off);
    }
    ushortx8 hr = hbf[d];
    float hv[8];
#pragma unroll
    for (int c = 0; c < 8; ++c) hv[c] = bfbits2f((unsigned short)hr[c]);
    float v = ldf(b2, q, isbf);
#pragma unroll
    for (int c = 0; c < 8; ++c)
        v += a[c] * ldf(W2r, c * 16 + q, isbf)
           + hv[c] * ldf(W2o, c * 16 + q, isbf);
    xs[d * 16 + q] = f2bfbits(selu_f(v));
}

// per-lane candidate ROW index: lane half-group hp=half>>1 selects endpoint.
// c64: low 32 bits of int64 little-endian at int-index 2*(2c+hp).
__device__ __forceinline__ int ld_candrow(const void* cand, int c, int hp, int c64) {
    const int* ci = (const int*)cand;
    return c64 ? ci[(2 * c + hp) * 2] : ci[2 * c + hp];
}

// ---- FC head: persistent waves, 4-deep software-pipelined gather.
//      R14: re-merged into a single dispatch (split was diagnostic only). --
__global__ __launch_bounds__(256, 5) void k_fc(const unsigned short* __restrict__ xs,
        const void* __restrict__ cand,
        const void* __restrict__ Wfc1, const void* __restrict__ bfc1,
        const void* __restrict__ Wfc2, const void* __restrict__ bfc2,
        void* __restrict__ out, const int* __restrict__ flags) {
    const float LAM = 1.0507009873554805f;
    const float ALA = 1.7580993408473766f;  // LAM * ALPHA
    const float L2E = 1.44269504088896340736f;
    const float AR2 = 1.6732632423543772f * 1.44269504088896340736f;  // ALPHA*L2E
    const float SCL = 1.0507009873554805f / 1.44269504088896340736f;  // LAM/L2E
    int lane = threadIdx.x & 63;
    int wid = (blockIdx.x * blockDim.x + threadIdx.x) >> 6;
    int m = lane & 15;
    int half = lane >> 4;
    int isbf = flags[0], c64 = flags[1];

    short8 wfrag[4];
    floatx4 cbias[4];
    float w2s[4][4];
    float c_corr;
    if (isbf) {
        const unsigned short* W1p = (const unsigned short*)Wfc1;
#pragma unroll
        for (int t = 0; t < 4; ++t)
#pragma unroll
            for (int j = 0; j < 8; ++j)
                wfrag[t][j] = (short)f2bfbits(
                    bfbits2f(W1p[(half * 8 + j) * 64 + t * 16 + m]) * L2E);
        const unsigned short* b1p = (const unsigned short*)bfc1;
        const unsigned short* w2p = (const unsigned short*)Wfc2;
        float asum = 0.f;
#pragma unroll
        for (int t = 0; t < 4; ++t)
#pragma unroll
            for (int r = 0; r < 4; ++r) {
                int h = t * 16 + half * 4 + r;
                cbias[t][r] = bfbits2f(b1p[h]) * L2E;
                float w2 = bfbits2f(w2p[h]);
                w2s[t][r] = w2 * SCL;
                asum += w2 * ALA;
            }
        asum += __shfl_xor(asum, 16, 64);
        asum += __shfl_xor(asum, 32, 64);
        c_corr = bfbits2f(((const unsigned short*)bfc2)[0]) - asum;
    } else {
        const float* W1p = (const float*)Wfc1;
#pragma unroll
        for (int t = 0; t < 4; ++t)
#pragma unroll
            for (int j = 0; j < 8; ++j)
                wfrag[t][j] = (short)f2bfbits(
                    W1p[(half * 8 + j) * 64 + t * 16 + m] * L2E);
        const float* b1p = (const float*)bfc1;
        const float* w2p = (const float*)Wfc2;
        float asum = 0.f;
#pragma unroll
        for (int t = 0; t < 4; ++t)
#pragma unroll
            for (int r = 0; r < 4; ++r) {
                int h = t * 16 + half * 4 + r;
                cbias[t][r] = b1p[h] * L2E;
                float w2 = w2p[h];
                w2s[t][r] = w2 * SCL;
                asum += w2 * ALA;
            }
        asum += __shfl_xor(asum, 16, 64);
        asum += __shfl_xor(asum, 32, 64);
        c_corr = ((const float*)bfc2)[0] - asum;
    }

    const int nTiles = NC / 16;
    int nW = (gridDim.x * blockDim.x) >> 6;
    if (wid >= nTiles) return;

    int half1 = half & 1;
    int hp = half >> 1;
    // 4-deep gather pipeline: af for tiles wid..wid+3nW in flight; row-index
    // queue one tile further ahead.
    int t1 = wid + nW, t2 = wid + 2 * nW, t3 = wid + 3 * nW, t4 = wid + 4 * nW;
    int r0i = ld_candrow(cand, wid * 16 + m, hp, c64);
    int r1i = ld_candrow(cand, ((t1 < nTiles) ? t1 : wid) * 16 + m, hp, c64);
    int r2i = ld_candrow(cand, ((t2 < nTiles) ? t2 : wid) * 16 + m, hp, c64);
    int r3i = ld_candrow(cand, ((t3 < nTiles) ? t3 : wid) * 16 + m, hp, c64);
    int r4i = ld_candrow(cand, ((t4 < nTiles) ? t4 : wid) * 16 + m, hp, c64);
    {
        short8 af0 = *(const short8*)(xs + r0i * 16 + half1 * 8);
        short8 af1 = *(const short8*)(xs + r1i * 16 + half1 * 8);
        short8 af2 = *(const short8*)(xs + r2i * 16 + half1 * 8);
        short8 af3 = *(const short8*)(xs + r3i * 16 + half1 * 8);

#pragma unroll 2
        for (int t = wid; t < nTiles; t += nW) {
            int tn5 = t + 5 * nW;
            int r5i = ld_candrow(cand, ((tn5 < nTiles) ? tn5 : t) * 16 + m, hp, c64);
            short8 af4 = *(const short8*)(xs + r4i * 16 + half1 * 8);

            float ps[4];
#pragma unroll
            for (int tt = 0; tt < 4; ++tt) {
                floatx4 ac = __builtin_amdgcn_mfma_f32_16x16x32_bf16(
                    wfrag[tt], af0, cbias[tt], 0, 0, 0);
                float s = 0.f;
#pragma unroll
                for (int r = 0; r < 4; ++r) {
                    float v = ac[r];
                    float mx = fmaxf(v, 0.f);
                    float e = __builtin_amdgcn_exp2f(fminf(v, 0.f));
                    s = fmaf(w2s[tt][r], fmaf(AR2, e, mx), s);
                }
                ps[tt] = s;
            }
            float part = (ps[0] + ps[1]) + (ps[2] + ps[3]);
            part += __shfl_xor(part, 16, 64);
            part += __shfl_xor(part, 32, 64);
            if (half == 0) {
                float o = part + c_corr;
                if (isbf) ((unsigned short*)out)[t * 16 + m] = f2bfbits(o);
                else ((float*)out)[t * 16 + m] = o;
            }
            af0 = af1;
            af1 = af2;
            af2 = af3;
            af3 = af4;
            r4i = r5i;
        }
    }
}

extern "C" void kernel_launch(void* const* d_in, const int* in_sizes, int n_in,
                              void* d_out, int out_size, void* d_ws, size_t ws_size,
                              hipStream_t stream) {
    const void* x_u = d_in[0];
    const void* x_g = d_in[1];
    const void* cand = d_in[2];
    const void* edges = d_in[3];
    const void* W1r = d_in[4];
    const void* W1o = d_in[5];
    const void* b1 = d_in[6];
    const void* W2r = d_in[7];
    const void* W2o = d_in[8];
    const void* b2 = d_in[9];
    const void* Wun = d_in[10];
    const void* bun = d_in[11];
    const void* Wfc1 = d_in[12];
    const void* bfc1 = d_in[13];
    const void* Wfc2 = d_in[14];
    const void* bfc2 = d_in[15];

    char* ws = (char*)d_ws;
    int* flags = (int*)ws;                                  // 64 B
    int* gcur = (int*)(ws + 64);                            // 782*4 -> 3200 B
    unsigned int* glist = (unsigned int*)(ws + 4160);       // 16.01 MB
    size_t glist_bytes = (size_t)NBK * CAP * 4;             // 16010240
    char* p = ws + 4160 + glist_bytes;
    int* dstoff = (int*)p;                                  // 400 KB
    int* ddeg = (int*)(p + 400000);                         // 400 KB
    unsigned short* hbf = (unsigned short*)(p + 800000);    // 1.6 MB
    unsigned short* xs = (unsigned short*)(p + 2400000);    // 6.4 MB

    hipMemsetAsync(gcur, 0, 3200, stream);

    k_bin1<<<(NE + B1CH - 1) / B1CH, 256, 0, stream>>>(edges, gcur, glist);
    k_sort<<<NBK, 256, 0, stream>>>(gcur, glist, dstoff, ddeg,
                                    (const unsigned int*)x_u,
                                    (const unsigned int*)cand,
                                    (const unsigned int*)edges, flags);
    k_gather1<<<(16 * NG + 255) / 256, 256, 0, stream>>>(dstoff, ddeg, glist, x_g,
                                                         W1r, W1o, b1, hbf, flags);
    k_gather2<<<G2BLK + UCBLK, 256, 0, stream>>>(dstoff, ddeg, glist,
                                                 (const ushortx8*)hbf,
                                                 W2r, W2o, b2, xs,
                                                 x_u, Wun, bun, flags);
    k_fc<<<1280, 256, 0, stream>>>(xs, cand, Wfc1, bfc1, Wfc2, bfc2, d_out, flags);
}